// Round 20
// baseline (661.754 us; speedup 1.0000x reference)
//
#include <hip/hip_runtime.h>

// Codred forward. R19 = R18 + residual fused into split-K GEMM slice-0
// epilogue: wo/ff2 slice0 computes acc+bias+x[row][col] (coalesced fp32 read
// overlapped with MFMA drain); add_ln2 then reads only tb+tb1 (was x+tb+tb1).
// Bitwise-identical numerics (fp32 2-operand commutativity). -39MB LN traffic.
// Config otherwise = R16/R18 best: NS=3 flash-decode, head-major kvh, single-q
// attn (R11 structure), vectorized combine/alpha, split-K wo/ff2, wave-LN,
// dbuf GEMM, swizzled Vt, Q-in-regs, defer-max, scaled-Q.

#define D    768
#define H    8
#define DKD  96
#define LAY  4
#define FFD  1024
#define NREL 97
#define BAG  8
#define SPANS 5
#define E    40
#define TT   1600
#define SEQ  512
#define D3   2304   // fused qkv width
#define NS   3      // kv chunks
#define QT   (TT / 64)

typedef __attribute__((ext_vector_type(8))) short bf16x8;
typedef __attribute__((ext_vector_type(4))) float f32x4;
typedef unsigned short ushort_t;
typedef unsigned int uint_t;

__device__ __forceinline__ ushort_t f2b(float x) {
    uint_t u = __builtin_bit_cast(uint_t, x);
    return (ushort_t)((u + 0x7fffu + ((u >> 16) & 1u)) >> 16);   // RNE
}
__device__ __forceinline__ float b2f(ushort_t v) {
    return __builtin_bit_cast(float, (uint_t)v << 16);
}

__device__ __forceinline__ void gload16(const void* g, void* l) {
    __builtin_amdgcn_global_load_lds(
        (const __attribute__((address_space(1))) unsigned int*)g,
        (__attribute__((address_space(3))) unsigned int*)l, 16, 0, 0);
}

// ---------------- block reductions (256 thr) --------------------------------
__device__ __forceinline__ float block_sum(float v, float* red) {
#pragma unroll
    for (int o = 32; o >= 1; o >>= 1) v += __shfl_xor(v, o);
    __syncthreads();
    if ((threadIdx.x & 63) == 0) red[threadIdx.x >> 6] = v;
    __syncthreads();
    return red[0] + red[1] + red[2] + red[3];
}

// ---------------- span max-pool, phase 1 ------------------------------------
__global__ __launch_bounds__(256) void span_pool_p1(const float* __restrict__ emb,
        const int* __restrict__ spans, float* __restrict__ partial) {
    const int e = blockIdx.x, pg = blockIdx.y;
    const int bag = e / SPANS;
    const int st = spans[e * 2 + 0];
    const int en = spans[e * 2 + 1];
    const int p0 = max(st, pg * 64);
    const int p1 = min(en, pg * 64 + 63);
    const int tid = threadIdx.x;
    if (tid >= 192) return;
    float4 m = make_float4(-1e30f, -1e30f, -1e30f, -1e30f);
    for (int p = p0; p <= p1; ++p) {
        const float4 v = *(const float4*)(emb + ((size_t)bag * SEQ + p) * D + tid * 4);
        m.x = fmaxf(m.x, v.x); m.y = fmaxf(m.y, v.y);
        m.z = fmaxf(m.z, v.z); m.w = fmaxf(m.w, v.w);
    }
    *(float4*)(partial + ((size_t)e * 8 + pg) * D + tid * 4) = m;
}

// ---------------- span max-pool, phase 2 -> bf16 htb ------------------------
__global__ __launch_bounds__(256) void span_pool_p2(const float* __restrict__ partial,
        ushort_t* __restrict__ htb) {
    const int e = blockIdx.x;
    const int tid = threadIdx.x;
    if (tid >= 192) return;
    float4 m = make_float4(-1e30f, -1e30f, -1e30f, -1e30f);
#pragma unroll
    for (int pg = 0; pg < 8; ++pg) {
        const float4 v = *(const float4*)(partial + ((size_t)e * 8 + pg) * D + tid * 4);
        m.x = fmaxf(m.x, v.x); m.y = fmaxf(m.y, v.y);
        m.z = fmaxf(m.z, v.z); m.w = fmaxf(m.w, v.w);
    }
    ushort4 o;
    o.x = f2b(m.x); o.y = f2b(m.y); o.z = f2b(m.z); o.w = f2b(m.w);
    *(ushort4*)(htb + (size_t)e * D + tid * 4) = o;
}

// ---------------- alpha: a[ij][d] = relu(u[i][d]+v[j][d]) (vectorized) ------
__global__ __launch_bounds__(256) void alpha_k(const float* __restrict__ uv,
        ushort_t* __restrict__ a) {
    const int ij = blockIdx.x;
    const int i = ij / E, j = ij % E;
    const int tid = threadIdx.x;
    if (tid >= 192) return;              // 192 threads x float4 = 768 cols
    const float4 uu = *(const float4*)(uv + (size_t)i * 1536 + tid * 4);
    const float4 vv = *(const float4*)(uv + (size_t)j * 1536 + 768 + tid * 4);
    ushort4 o;
    o.x = f2b(fmaxf(uu.x + vv.x, 0.f));
    o.y = f2b(fmaxf(uu.y + vv.y, 0.f));
    o.z = f2b(fmaxf(uu.z + vv.z, 0.f));
    o.w = f2b(fmaxf(uu.w + vv.w, 0.f));
    *(ushort4*)(a + (size_t)ij * D + tid * 4) = o;
}

// ---------------- upfront transpose: z=0 lnr, z=1 wu, z=2 wvv ---------------
__global__ __launch_bounds__(256) void transpose_up(const float* __restrict__ lnr,
        const float* __restrict__ wu, const float* __restrict__ wvv,
        ushort_t* __restrict__ lnrT, ushort_t* __restrict__ wuvT) {
    __shared__ float t[32][33];
    const int z = blockIdx.z;
    const float* src = (z == 0) ? lnr : (z == 1) ? wu : wvv;
    ushort_t* dst = (z == 0) ? lnrT : wuvT + (size_t)(z - 1) * D * D;
    const int n0 = blockIdx.x * 32, k0 = blockIdx.y * 32;
    const int tx = threadIdx.x & 31, ty = threadIdx.x >> 5;
#pragma unroll
    for (int i = 0; i < 4; ++i)
        t[ty + i * 8][tx] = src[(size_t)(k0 + ty + i * 8) * D + n0 + tx];
    __syncthreads();
#pragma unroll
    for (int i = 0; i < 4; ++i)
        dst[(size_t)(n0 + ty + i * 8) * D + k0 + tx] = f2b(t[tx][ty + i * 8]);
}

// ---------------- per-layer fused transpose: z 0..3 wq/wk/wv/wo, 4 w1, 5 w2 -
__global__ __launch_bounds__(256) void transpose_layer(const float* __restrict__ wq,
        const float* __restrict__ wk, const float* __restrict__ wv,
        const float* __restrict__ wo, const float* __restrict__ w1,
        const float* __restrict__ w2, int l, ushort_t* __restrict__ wT4,
        ushort_t* __restrict__ w1T, ushort_t* __restrict__ w2T) {
    __shared__ float t[32][33];
    const int z = blockIdx.z;
    const float* src; ushort_t* dst; int K, N;
    if (z < 4) {
        K = D; N = D;
        src = (z == 0 ? wq : z == 1 ? wk : z == 2 ? wv : wo) + (size_t)l * D * D;
        dst = wT4 + (size_t)z * D * D;
    } else if (z == 4) {
        K = D; N = FFD; src = w1 + (size_t)l * D * FFD; dst = w1T;
    } else {
        K = FFD; N = D; src = w2 + (size_t)l * FFD * D; dst = w2T;
    }
    const int n0 = blockIdx.x * 32, k0 = blockIdx.y * 32;
    if (n0 >= N || k0 >= K) return;
    const int tx = threadIdx.x & 31, ty = threadIdx.x >> 5;
#pragma unroll
    for (int i = 0; i < 4; ++i)
        t[ty + i * 8][tx] = src[(size_t)(k0 + ty + i * 8) * N + n0 + tx];
    __syncthreads();
#pragma unroll
    for (int i = 0; i < 4; ++i)
        dst[(size_t)(n0 + ty + i * 8) * K + k0 + tx] = f2b(t[tx][ty + i * 8]);
}

// ---------------- biases: bqkv [L][2304], buv [1536] -------------------------
__global__ __launch_bounds__(256) void concat_bias(const float* __restrict__ bq,
        const float* __restrict__ bk, const float* __restrict__ bv,
        const float* __restrict__ bu, const float* __restrict__ bvv,
        float* __restrict__ bqkv, float* __restrict__ buv) {
    const int i = blockIdx.x * 256 + threadIdx.x;
    if (i < LAY * D3) {
        const int l = i / D3, j = i % D3;
        bqkv[i] = j < D ? bq[l * D + j] : j < 2 * D ? bk[l * D + j - D] : bv[l * D + j - 2 * D];
    }
    const int k = i - LAY * D3;
    if (k >= 0 && k < 2 * D) buv[k] = k < D ? bu[k] : bvv[k - D];
}

// ---------------- bf16 MFMA GEMM: C = A[M,K] @ Bt[N,K]^T + bias -------------
// 128x64 tile, BK=32, dbuf 2-phase, global_load_lds. SPLITK: grid.z=2 slices;
// slice0 adds bias (+ residual Rsd if non-null). HEADMAJ: kvh[3][H][TT][96].
template<int RELU, int SCALEQ, int SPLITK, int HEADMAJ>
__global__ __launch_bounds__(256) void gemm_mfma(const ushort_t* __restrict__ A,
        const ushort_t* __restrict__ Bt, const float* __restrict__ bias,
        const float* __restrict__ Rsd,
        float* __restrict__ Cf, float* __restrict__ Cf1,
        ushort_t* __restrict__ Cb, int M, int N, int K) {
    __shared__ ushort_t As[2][128 * 32];   // linear: row*32 + col
    __shared__ ushort_t Bs[2][64 * 32];
    const int tid = threadIdx.x;
    const int lane = tid & 63, w = tid >> 6;
    const int l15 = lane & 15, lg = lane >> 4;
    const int bm = blockIdx.y * 128, bn = blockIdx.x * 64;
    const int wm = (w >> 1) * 64, wn = (w & 1) * 32;
    const int trA0 = w * 32 + (lane >> 2);
    const int trA1 = trA0 + 16;
    const int trB  = w * 16 + (lane >> 2);
    const int sc   = (lane & 3) * 8;
    const size_t rowA0 = (size_t)min(bm + trA0, M - 1) * K;
    const size_t rowA1 = (size_t)min(bm + trA1, M - 1) * K;
    const size_t rowB  = (size_t)(bn + trB) * K;
    const int kbeg = SPLITK ? blockIdx.z * (K / 2) : 0;
    const int kend = SPLITK ? kbeg + K / 2 : K;

    f32x4 acc[4][2];
#pragma unroll
    for (int mi = 0; mi < 4; ++mi)
#pragma unroll
        for (int ni = 0; ni < 2; ++ni)
            acc[mi][ni] = (f32x4){0.f, 0.f, 0.f, 0.f};

    auto STAGE = [&](int buf, int k0) {
        gload16(A + rowA0 + k0 + sc, As[buf] + w * 1024);
        gload16(A + rowA1 + k0 + sc, As[buf] + w * 1024 + 512);
        gload16(Bt + rowB + k0 + sc, Bs[buf] + w * 512);
    };

    const int ntk = (kend - kbeg) / 32;
    STAGE(0, kbeg);
    __syncthreads();                       // vmcnt(0) drain: buf0 ready
    for (int t = 0; t < ntk; ++t) {
        const int buf = t & 1;
        if (t + 1 < ntk) STAGE(buf ^ 1, kbeg + (t + 1) * 32);
        bf16x8 af[4], bfr[2];
#pragma unroll
        for (int mi = 0; mi < 4; ++mi)
            af[mi] = *(const bf16x8*)&As[buf][(wm + mi * 16 + l15) * 32 + lg * 8];
#pragma unroll
        for (int ni = 0; ni < 2; ++ni)
            bfr[ni] = *(const bf16x8*)&Bs[buf][(wn + ni * 16 + l15) * 32 + lg * 8];
        __builtin_amdgcn_s_setprio(1);
#pragma unroll
        for (int mi = 0; mi < 4; ++mi)
#pragma unroll
            for (int ni = 0; ni < 2; ++ni)
                acc[mi][ni] = __builtin_amdgcn_mfma_f32_16x16x32_bf16(
                    af[mi], bfr[ni], acc[mi][ni], 0, 0, 0);
        __builtin_amdgcn_s_setprio(0);
        __syncthreads();                   // drains next-buf staging; guards reuse
    }
    float* Cout = (SPLITK && blockIdx.z) ? Cf1 : Cf;
    const bool addb = !(SPLITK && blockIdx.z);
#pragma unroll
    for (int mi = 0; mi < 4; ++mi)
#pragma unroll
        for (int ni = 0; ni < 2; ++ni)
#pragma unroll
            for (int r = 0; r < 4; ++r) {
                const int row = bm + wm + mi * 16 + lg * 4 + r;
                if (row >= M) continue;
                const int col = bn + wn + ni * 16 + l15;
                float v = acc[mi][ni][r] + (addb ? bias[col] : 0.f);
                if (addb && Rsd) v += Rsd[(size_t)row * N + col];   // fused residual
                if (RELU) v = fmaxf(v, 0.f);
                if (SCALEQ) { if (col < D) v *= 0.10206207261596577f; }
                if (Cout) Cout[(size_t)row * N + col] = v;
                if (Cb) {
                    if (HEADMAJ) {
                        const int m = col / D;            // 0=q 1=k 2=v
                        const int rem = col - m * D;
                        const int hd = rem / DKD;
                        const int dd = rem - hd * DKD;
                        Cb[(((size_t)m * H + hd) * TT + row) * DKD + dd] = f2b(v);
                    } else {
                        Cb[(size_t)row * N + col] = f2b(v);
                    }
                }
            }
}

// ---------------- flash-decoding attention over a KV chunk ------------------
// R11 structure; head-major kvh[3][H][TT][96]; grid (25, 8, 3).
__global__ __launch_bounds__(256) void attn_part(const ushort_t* __restrict__ kvh,
        ushort_t* __restrict__ Opart, float* __restrict__ ml) {
    __shared__ ushort_t Ks[64][104];     // K tile; reused as O-repack scratch
    __shared__ ushort_t Vt[96][72];      // transposed V, XOR slot swizzle
    __shared__ ushort_t Ps[4][16][72];   // per-wave P tile
    const int q0 = blockIdx.x * 64;
    const int h = blockIdx.y;
    const int cch = blockIdx.z;
    const int t_lo = (cch * QT) / NS;
    const int t_hi = ((cch + 1) * QT) / NS;
    const int tid = threadIdx.x;
    const int lane = tid & 63, w = tid >> 6;
    const int l15 = lane & 15, lg = lane >> 4;

    const ushort_t* Qb = kvh + (size_t)h * TT * DKD;
    const ushort_t* Kb = kvh + ((size_t)H + h) * TT * DKD;
    const ushort_t* Vb = kvh + ((size_t)2 * H + h) * TT * DKD;

    int r_[3], c_[3];
#pragma unroll
    for (int i = 0; i < 3; ++i) {
        const int ch = i * 256 + tid;
        r_[i] = ch / 12; c_[i] = (ch % 12) * 8;
    }
    // Q fragments in registers (pre-scaled by 1/sqrt(96))
    bf16x8 qfrag[3];
#pragma unroll
    for (int ks = 0; ks < 3; ++ks)
        qfrag[ks] = *(const bf16x8*)(Qb + (size_t)(q0 + w * 16 + l15) * DKD
                                     + ks * 32 + lg * 8);
    // prologue: first K/V tile into regs
    uint4 kreg[3], vreg[3];
    {
        const int s0 = t_lo * 64;
#pragma unroll
        for (int i = 0; i < 3; ++i) {
            kreg[i] = *(const uint4*)(Kb + (size_t)(s0 + r_[i]) * DKD + c_[i]);
            vreg[i] = *(const uint4*)(Vb + (size_t)(s0 + r_[i]) * DKD + c_[i]);
        }
    }
    float m_run[4], l_run[4];
    f32x4 acc_o[6];
#pragma unroll
    for (int r = 0; r < 4; ++r) { m_run[r] = -1e30f; l_run[r] = 0.f; }
#pragma unroll
    for (int nt = 0; nt < 6; ++nt) acc_o[nt] = (f32x4){0.f, 0.f, 0.f, 0.f};

    for (int t = t_lo; t < t_hi; ++t) {
        __syncthreads();                 // prev tile consumed
#pragma unroll
        for (int i = 0; i < 3; ++i) {
            *(uint4*)&Ks[r_[i]][c_[i]] = kreg[i];
            const ushort_t* pv = (const ushort_t*)&vreg[i];
            const int kk = r_[i] ^ (((c_[i] >> 3) & 7) << 3);   // slot swizzle
#pragma unroll
            for (int j = 0; j < 8; ++j) Vt[c_[i] + j][kk] = pv[j];
        }
        __syncthreads();
        if (t + 1 < t_hi) {              // issue next-tile loads early (T14)
            const int s0 = (t + 1) * 64;
#pragma unroll
            for (int i = 0; i < 3; ++i) {
                kreg[i] = *(const uint4*)(Kb + (size_t)(s0 + r_[i]) * DKD + c_[i]);
                vreg[i] = *(const uint4*)(Vb + (size_t)(s0 + r_[i]) * DKD + c_[i]);
            }
        }
        // S = Q K^T
        f32x4 accs[4];
#pragma unroll
        for (int ni = 0; ni < 4; ++ni) accs[ni] = (f32x4){0.f, 0.f, 0.f, 0.f};
        __builtin_amdgcn_s_setprio(1);
#pragma unroll
        for (int ks = 0; ks < 3; ++ks) {
#pragma unroll
            for (int ni = 0; ni < 4; ++ni) {
                const bf16x8 bk = *(const bf16x8*)&Ks[ni * 16 + l15][ks * 32 + lg * 8];
                accs[ni] = __builtin_amdgcn_mfma_f32_16x16x32_bf16(qfrag[ks], bk, accs[ni], 0, 0, 0);
            }
        }
        __builtin_amdgcn_s_setprio(0);
        // online softmax with defer-max (T13, THR=8)
        float mx[4];
#pragma unroll
        for (int r = 0; r < 4; ++r) {
            mx[r] = fmaxf(fmaxf(accs[0][r], accs[1][r]), fmaxf(accs[2][r], accs[3][r]));
#pragma unroll
            for (int o = 1; o <= 8; o <<= 1) mx[r] = fmaxf(mx[r], __shfl_xor(mx[r], o));
        }
        const bool grow = (mx[0] > m_run[0] + 8.f) || (mx[1] > m_run[1] + 8.f) ||
                          (mx[2] > m_run[2] + 8.f) || (mx[3] > m_run[3] + 8.f);
        if (__any(grow)) {
#pragma unroll
            for (int r = 0; r < 4; ++r) {
                const float mnew = fmaxf(m_run[r], mx[r]);
                const float sf = __expf(m_run[r] - mnew);
                m_run[r] = mnew;
                l_run[r] *= sf;
#pragma unroll
                for (int nt = 0; nt < 6; ++nt) acc_o[nt][r] *= sf;
            }
        }
        float ps[4][4];
#pragma unroll
        for (int r = 0; r < 4; ++r) {
            float rs = 0.f;
#pragma unroll
            for (int ni = 0; ni < 4; ++ni) {
                ps[ni][r] = __expf(accs[ni][r] - m_run[r]);
                rs += ps[ni][r];
            }
#pragma unroll
            for (int o = 1; o <= 8; o <<= 1) rs += __shfl_xor(rs, o);
            l_run[r] += rs;
        }
#pragma unroll
        for (int ni = 0; ni < 4; ++ni)
#pragma unroll
            for (int r = 0; r < 4; ++r)
                Ps[w][lg * 4 + r][ni * 16 + l15] = f2b(ps[ni][r]);
        // O += P @ V
        __builtin_amdgcn_s_setprio(1);
#pragma unroll
        for (int ks = 0; ks < 2; ++ks) {
            const bf16x8 ap = *(const bf16x8*)&Ps[w][l15][ks * 32 + lg * 8];
#pragma unroll
            for (int nt = 0; nt < 6; ++nt) {
                const int dim = nt * 16 + l15;
                const int kcol = (ks * 32 + lg * 8) ^ (((dim >> 3) & 7) << 3);
                const bf16x8 bv = *(const bf16x8*)&Vt[dim][kcol];
                acc_o[nt] = __builtin_amdgcn_mfma_f32_16x16x32_bf16(ap, bv, acc_o[nt], 0, 0, 0);
            }
        }
        __builtin_amdgcn_s_setprio(0);
    }
    // ---- epilogue: repack O via dead Ks LDS, then coalesced uint4 stores ----
    __syncthreads();                      // all waves done with Ks/Vt
    ushort_t* scr = &Ks[0][0] + w * (16 * 104);   // per-wave [16][104]
#pragma unroll
    for (int nt = 0; nt < 6; ++nt)
#pragma unroll
        for (int r = 0; r < 4; ++r)
            scr[(lg * 4 + r) * 104 + nt * 16 + l15] = f2b(acc_o[nt][r]);
    const size_t obase = (((size_t)cch * H + h) * TT + q0 + w * 16) * DKD;
#pragma unroll
    for (int ch = 0; ch < 3; ++ch) {
        const int idx = ch * 64 + lane;   // 0..191
        const int row = idx / 12;         // 0..15
        const int c16 = (idx % 12) * 8;   // 0..88 step 8
        const uint4 v = *(const uint4*)&scr[row * 104 + c16];
        *(uint4*)(Opart + obase + (size_t)row * DKD + c16) = v;
    }
    if (l15 == 0) {
#pragma unroll
        for (int r = 0; r < 4; ++r) {
            const int row = q0 + w * 16 + lg * 4 + r;
            float2* mlp = (float2*)ml;
            mlp[((size_t)cch * H + h) * TT + row] = make_float2(m_run[r], l_run[r]);
        }
    }
}

// ---------------- combine NS partials, wave-per-row, vectorized -------------
__global__ __launch_bounds__(256) void attn_combine(const ushort_t* __restrict__ Opart,
        const float* __restrict__ ml, ushort_t* __restrict__ O) {
    const int lane = threadIdx.x & 63, w = threadIdx.x >> 6;
    const int row = blockIdx.x * 4 + w;
    const int hd = lane >> 3;            // head
    const int co = (lane & 7) * 12;      // col offset within head
    const float2* mlp = (const float2*)ml;
    float m[NS], l[NS], M = -1e30f;
#pragma unroll
    for (int c = 0; c < NS; ++c) {
        const float2 v = mlp[((size_t)c * H + hd) * TT + row];
        m[c] = v.x; l[c] = v.y; M = fmaxf(M, m[c]);
    }
    float e[NS], L = 0.f;
#pragma unroll
    for (int c = 0; c < NS; ++c) { e[c] = __expf(m[c] - M); L += l[c] * e[c]; }
    const float invL = 1.f / L;
    float o[12] = {};
#pragma unroll
    for (int c = 0; c < NS; ++c) {
        const ushort_t* p = Opart + (((size_t)c * H + hd) * TT + row) * DKD + co;
#pragma unroll
        for (int j = 0; j < 3; ++j) {
            const ushort4 v4 = *(const ushort4*)(p + j * 4);
            o[j * 4 + 0] += b2f(v4.x) * e[c];
            o[j * 4 + 1] += b2f(v4.y) * e[c];
            o[j * 4 + 2] += b2f(v4.z) * e[c];
            o[j * 4 + 3] += b2f(v4.w) * e[c];
        }
    }
    ushort_t* q = O + (size_t)row * D + hd * DKD + co;
#pragma unroll
    for (int j = 0; j < 3; ++j) {
        ushort4 u;
        u.x = f2b(o[j * 4 + 0] * invL); u.y = f2b(o[j * 4 + 1] * invL);
        u.z = f2b(o[j * 4 + 2] * invL); u.w = f2b(o[j * 4 + 3] * invL);
        *(ushort4*)(q + j * 4) = u;
    }
}

// ---------------- x = LN(y0 + y1); y0 already holds x+bias+acc0 -------------
__global__ __launch_bounds__(256) void add_ln2(float* __restrict__ x,
        const float* __restrict__ y0, const float* __restrict__ y1,
        const float* __restrict__ g, const float* __restrict__ b,
        ushort_t* __restrict__ xb) {
    const int lane = threadIdx.x & 63, w = threadIdx.x >> 6;
    const int row = blockIdx.x * 4 + w;
    const size_t base = (size_t)row * D;
    float4 t[3];
    float s = 0.f, s2 = 0.f;
#pragma unroll
    for (int i = 0; i < 3; ++i) {
        const int c = lane * 4 + i * 256;
        const float4 a0 = *(const float4*)(y0 + base + c);
        const float4 a1 = *(const float4*)(y1 + base + c);
        t[i].x = a0.x + a1.x; t[i].y = a0.y + a1.y;
        t[i].z = a0.z + a1.z; t[i].w = a0.w + a1.w;
        s += t[i].x + t[i].y + t[i].z + t[i].w;
        s2 += t[i].x * t[i].x + t[i].y * t[i].y + t[i].z * t[i].z + t[i].w * t[i].w;
    }
#pragma unroll
    for (int o = 32; o >= 1; o >>= 1) { s += __shfl_xor(s, o); s2 += __shfl_xor(s2, o); }
    const float mean = s * (1.f / 768.f);
    const float var = s2 * (1.f / 768.f) - mean * mean;
    const float inv = rsqrtf(var + 1e-5f);
#pragma unroll
    for (int i = 0; i < 3; ++i) {
        const int c = lane * 4 + i * 256;
        float4 o4;
        o4.x = (t[i].x - mean) * inv * g[c + 0] + b[c + 0];
        o4.y = (t[i].y - mean) * inv * g[c + 1] + b[c + 1];
        o4.z = (t[i].z - mean) * inv * g[c + 2] + b[c + 2];
        o4.w = (t[i].w - mean) * inv * g[c + 3] + b[c + 3];
        *(float4*)(x + base + c) = o4;
        ushort4 u;
        u.x = f2b(o4.x); u.y = f2b(o4.y); u.z = f2b(o4.z); u.w = f2b(o4.w);
        *(ushort4*)(xb + base + c) = u;
    }
}

// ---------------- predictor -------------------------------------------------
__global__ __launch_bounds__(256) void predict_k(const float* __restrict__ x,
        const float* __restrict__ pw, const float* __restrict__ pb,
        float* __restrict__ out) {
    __shared__ float red[4];
    const int r = blockIdx.x;
    const int tid = threadIdx.x;
    float best = -1e30f;
    for (int bag = 0; bag < BAG; ++bag) {
        const int row = (bag * SPANS) * E + (bag * SPANS + 1);
        const float* f = x + (size_t)row * D;
        float acc = 0.f;
        for (int d = tid; d < D; d += 256) acc += f[d] * pw[(size_t)d * NREL + r];
        best = fmaxf(best, block_sum(acc, red));
    }
    if (tid == 0) out[r] = best + pb[r];
}

extern "C" void kernel_launch(void* const* d_in, const int* in_sizes, int n_in,
                              void* d_out, int out_size, void* d_ws, size_t ws_size,
                              hipStream_t stream) {
    const float* emb  = (const float*)d_in[0];
    const int*  spans = (const int*)d_in[1];
    const float* wu_w = (const float*)d_in[2];  const float* wu_b = (const float*)d_in[3];
    const float* wvv_w= (const float*)d_in[4];  const float* wvv_b= (const float*)d_in[5];
    const float* lnr_w= (const float*)d_in[6];  const float* lnr_b= (const float*)d_in[7];
    const float* wq = (const float*)d_in[8];    const float* bq = (const float*)d_in[9];
    const float* wk = (const float*)d_in[10];   const float* bk = (const float*)d_in[11];
    const float* wv = (const float*)d_in[12];   const float* bv = (const float*)d_in[13];
    const float* wo = (const float*)d_in[14];   const float* bo = (const float*)d_in[15];
    const float* w1 = (const float*)d_in[16];   const float* b1 = (const float*)d_in[17];
    const float* w2 = (const float*)d_in[18];   const float* b2 = (const float*)d_in[19];
    const float* g1 = (const float*)d_in[20];   const float* be1= (const float*)d_in[21];
    const float* g2 = (const float*)d_in[22];   const float* be2= (const float*)d_in[23];
    const float* pw = (const float*)d_in[24];   const float* pb = (const float*)d_in[25];

    // workspace layout (~36 MB). Aliases: Opart = tb+fb; tb1 = kvh region.
    char* cur = (char*)d_ws;
    auto alloc = [&](size_t bytes) { char* p = cur; cur += (bytes + 255) & ~(size_t)255; return p; };
    ushort_t* htb  = (ushort_t*)alloc(E * D * 2);
    float*    uvb  = (float*)alloc((size_t)E * 1536 * 4);
    float*    part = (float*)alloc((size_t)E * 8 * D * 4);   // span partials; reused as ml
    float*    x    = (float*)alloc((size_t)TT * D * 4);
    ushort_t* xb   = (ushort_t*)alloc((size_t)TT * D * 2);
    ushort_t* kvh  = (ushort_t*)alloc((size_t)3 * H * TT * DKD * 2); // head-major QKV
    ushort_t* ob   = (ushort_t*)alloc((size_t)TT * D * 2);   // alpha, then attn out
    float*    tb   = (float*)alloc((size_t)TT * D * 4);      // adjacent ...
    ushort_t* fb   = (ushort_t*)alloc((size_t)TT * FFD * 2); // ... to tb
    ushort_t* wT4  = (ushort_t*)alloc((size_t)4 * D * D * 2);
    ushort_t* w1T  = (ushort_t*)alloc((size_t)D * FFD * 2);
    ushort_t* w2T  = (ushort_t*)alloc((size_t)FFD * D * 2);
    float*    bqkv = (float*)alloc((size_t)LAY * D3 * 4);
    float*    buv  = (float*)alloc((size_t)2 * D * 4);
    ushort_t* Opart = (ushort_t*)tb;    // NS*H*TT*DKD*2 = 7.37 MB <= tb+fb (8.2 MB)
    float*    ml    = part;             // 300 KB <= part
    ushort_t* wuvT  = wT4;              // [1536][768], used before layer 0
    ushort_t* lnrT  = w1T;              // [768][768], used before layer 0
    float*    tb1   = (float*)kvh;      // split-K partial; kvh dead when used

    const int DD = D * D;

    span_pool_p1<<<dim3(E, 8), 256, 0, stream>>>(emb, spans, part);
    span_pool_p2<<<E, 256, 0, stream>>>(part, htb);
    transpose_up<<<dim3(24, 24, 3), 256, 0, stream>>>(lnr_w, wu_w, wvv_w, lnrT, wuvT);
    concat_bias<<<(LAY * D3 + 2 * D + 255) / 256, 256, 0, stream>>>(bq, bk, bv, wu_b, wvv_b, bqkv, buv);
    gemm_mfma<0, 0, 0, 0><<<dim3(1536 / 64, 1), 256, 0, stream>>>(
        htb, wuvT, buv, nullptr, uvb, nullptr, nullptr, E, 1536, D);
    alpha_k<<<TT, 256, 0, stream>>>(uvb, ob);
    gemm_mfma<1, 0, 0, 0><<<dim3(D / 64, (TT + 127) / 128), 256, 0, stream>>>(
        ob, lnrT, lnr_b, nullptr, x, nullptr, xb, TT, D, D);

    for (int l = 0; l < LAY; ++l) {
        transpose_layer<<<dim3(32, 32, 6), 256, 0, stream>>>(wq, wk, wv, wo, w1, w2, l, wT4, w1T, w2T);
        // fused QKV projection, head-major bf16 out (Q pre-scaled by 1/sqrt(96))
        gemm_mfma<0, 1, 0, 1><<<dim3(D3 / 64, (TT + 127) / 128), 256, 0, stream>>>(
            xb, wT4, bqkv + l * D3, nullptr, nullptr, nullptr, kvh, TT, D3, D);
        attn_part<<<dim3(QT, H, NS), 256, 0, stream>>>(kvh, Opart, ml);
        attn_combine<<<TT / 4, 256, 0, stream>>>(Opart, ml, ob);
        // wo: split-K=2; slice0 adds bias + residual x -> tb; slice1 -> tb1
        gemm_mfma<0, 0, 1, 0><<<dim3(D / 64, (TT + 127) / 128, 2), 256, 0, stream>>>(
            ob, wT4 + 3 * DD, bo + l * D, x, tb, tb1, nullptr, TT, D, D);
        add_ln2<<<TT / 4, 256, 0, stream>>>(x, tb, tb1, g1 + l * D, be1 + l * D, xb);
        gemm_mfma<1, 0, 0, 0><<<dim3(FFD / 64, (TT + 127) / 128), 256, 0, stream>>>(
            xb, w1T, b1 + l * FFD, nullptr, nullptr, nullptr, fb, TT, FFD, D);
        // ff2: split-K=2; slice0 adds bias + residual x -> tb; slice1 -> tb1
        gemm_mfma<0, 0, 1, 0><<<dim3(D / 64, (TT + 127) / 128, 2), 256, 0, stream>>>(
            fb, w2T, b2 + l * D, x, tb, tb1, nullptr, TT, D, FFD);
        add_ln2<<<TT / 4, 256, 0, stream>>>(x, tb, tb1, g2 + l * D, be2 + l * D, xb);
    }

    predict_k<<<NREL, 256, 0, stream>>>(x, pw, pb, (float*)d_out);
    (void)in_sizes; (void)n_in; (void)out_size; (void)ws_size;
}

// Round 21
// 592.858 us; speedup vs baseline: 1.1162x; 1.1162x over previous
//
#include <hip/hip_runtime.h>

// Codred forward. R20 = FINAL: revert to R18 best config (R19's fused-residual
// GEMM epilogue added 32 exposed scalar loads/thread at the epilogue of a
// compute-bound kernel -> +66us). This is the session-best kernel (~594us,
// 10.5x over fp32 baseline):
//  NS=3 flash-decode attention (R11 structure: staged K + in-kernel swizzled
//  V-transpose, Q-in-regs, defer-max T13, scaled-Q), head-major kvh QKV,
//  vectorized combine/alpha/LN, split-K wo/ff2, dbuf global_load_lds GEMM.

#define D    768
#define H    8
#define DKD  96
#define LAY  4
#define FFD  1024
#define NREL 97
#define BAG  8
#define SPANS 5
#define E    40
#define TT   1600
#define SEQ  512
#define D3   2304   // fused qkv width
#define NS   3      // kv chunks
#define QT   (TT / 64)

typedef __attribute__((ext_vector_type(8))) short bf16x8;
typedef __attribute__((ext_vector_type(4))) float f32x4;
typedef unsigned short ushort_t;
typedef unsigned int uint_t;

__device__ __forceinline__ ushort_t f2b(float x) {
    uint_t u = __builtin_bit_cast(uint_t, x);
    return (ushort_t)((u + 0x7fffu + ((u >> 16) & 1u)) >> 16);   // RNE
}
__device__ __forceinline__ float b2f(ushort_t v) {
    return __builtin_bit_cast(float, (uint_t)v << 16);
}

__device__ __forceinline__ void gload16(const void* g, void* l) {
    __builtin_amdgcn_global_load_lds(
        (const __attribute__((address_space(1))) unsigned int*)g,
        (__attribute__((address_space(3))) unsigned int*)l, 16, 0, 0);
}

// ---------------- block reductions (256 thr) --------------------------------
__device__ __forceinline__ float block_sum(float v, float* red) {
#pragma unroll
    for (int o = 32; o >= 1; o >>= 1) v += __shfl_xor(v, o);
    __syncthreads();
    if ((threadIdx.x & 63) == 0) red[threadIdx.x >> 6] = v;
    __syncthreads();
    return red[0] + red[1] + red[2] + red[3];
}

// ---------------- span max-pool, phase 1 ------------------------------------
__global__ __launch_bounds__(256) void span_pool_p1(const float* __restrict__ emb,
        const int* __restrict__ spans, float* __restrict__ partial) {
    const int e = blockIdx.x, pg = blockIdx.y;
    const int bag = e / SPANS;
    const int st = spans[e * 2 + 0];
    const int en = spans[e * 2 + 1];
    const int p0 = max(st, pg * 64);
    const int p1 = min(en, pg * 64 + 63);
    const int tid = threadIdx.x;
    if (tid >= 192) return;
    float4 m = make_float4(-1e30f, -1e30f, -1e30f, -1e30f);
    for (int p = p0; p <= p1; ++p) {
        const float4 v = *(const float4*)(emb + ((size_t)bag * SEQ + p) * D + tid * 4);
        m.x = fmaxf(m.x, v.x); m.y = fmaxf(m.y, v.y);
        m.z = fmaxf(m.z, v.z); m.w = fmaxf(m.w, v.w);
    }
    *(float4*)(partial + ((size_t)e * 8 + pg) * D + tid * 4) = m;
}

// ---------------- span max-pool, phase 2 -> bf16 htb ------------------------
__global__ __launch_bounds__(256) void span_pool_p2(const float* __restrict__ partial,
        ushort_t* __restrict__ htb) {
    const int e = blockIdx.x;
    const int tid = threadIdx.x;
    if (tid >= 192) return;
    float4 m = make_float4(-1e30f, -1e30f, -1e30f, -1e30f);
#pragma unroll
    for (int pg = 0; pg < 8; ++pg) {
        const float4 v = *(const float4*)(partial + ((size_t)e * 8 + pg) * D + tid * 4);
        m.x = fmaxf(m.x, v.x); m.y = fmaxf(m.y, v.y);
        m.z = fmaxf(m.z, v.z); m.w = fmaxf(m.w, v.w);
    }
    ushort4 o;
    o.x = f2b(m.x); o.y = f2b(m.y); o.z = f2b(m.z); o.w = f2b(m.w);
    *(ushort4*)(htb + (size_t)e * D + tid * 4) = o;
}

// ---------------- alpha: a[ij][d] = relu(u[i][d]+v[j][d]) (vectorized) ------
__global__ __launch_bounds__(256) void alpha_k(const float* __restrict__ uv,
        ushort_t* __restrict__ a) {
    const int ij = blockIdx.x;
    const int i = ij / E, j = ij % E;
    const int tid = threadIdx.x;
    if (tid >= 192) return;              // 192 threads x float4 = 768 cols
    const float4 uu = *(const float4*)(uv + (size_t)i * 1536 + tid * 4);
    const float4 vv = *(const float4*)(uv + (size_t)j * 1536 + 768 + tid * 4);
    ushort4 o;
    o.x = f2b(fmaxf(uu.x + vv.x, 0.f));
    o.y = f2b(fmaxf(uu.y + vv.y, 0.f));
    o.z = f2b(fmaxf(uu.z + vv.z, 0.f));
    o.w = f2b(fmaxf(uu.w + vv.w, 0.f));
    *(ushort4*)(a + (size_t)ij * D + tid * 4) = o;
}

// ---------------- upfront transpose: z=0 lnr, z=1 wu, z=2 wvv ---------------
__global__ __launch_bounds__(256) void transpose_up(const float* __restrict__ lnr,
        const float* __restrict__ wu, const float* __restrict__ wvv,
        ushort_t* __restrict__ lnrT, ushort_t* __restrict__ wuvT) {
    __shared__ float t[32][33];
    const int z = blockIdx.z;
    const float* src = (z == 0) ? lnr : (z == 1) ? wu : wvv;
    ushort_t* dst = (z == 0) ? lnrT : wuvT + (size_t)(z - 1) * D * D;
    const int n0 = blockIdx.x * 32, k0 = blockIdx.y * 32;
    const int tx = threadIdx.x & 31, ty = threadIdx.x >> 5;
#pragma unroll
    for (int i = 0; i < 4; ++i)
        t[ty + i * 8][tx] = src[(size_t)(k0 + ty + i * 8) * D + n0 + tx];
    __syncthreads();
#pragma unroll
    for (int i = 0; i < 4; ++i)
        dst[(size_t)(n0 + ty + i * 8) * D + k0 + tx] = f2b(t[tx][ty + i * 8]);
}

// ---------------- per-layer fused transpose: z 0..3 wq/wk/wv/wo, 4 w1, 5 w2 -
__global__ __launch_bounds__(256) void transpose_layer(const float* __restrict__ wq,
        const float* __restrict__ wk, const float* __restrict__ wv,
        const float* __restrict__ wo, const float* __restrict__ w1,
        const float* __restrict__ w2, int l, ushort_t* __restrict__ wT4,
        ushort_t* __restrict__ w1T, ushort_t* __restrict__ w2T) {
    __shared__ float t[32][33];
    const int z = blockIdx.z;
    const float* src; ushort_t* dst; int K, N;
    if (z < 4) {
        K = D; N = D;
        src = (z == 0 ? wq : z == 1 ? wk : z == 2 ? wv : wo) + (size_t)l * D * D;
        dst = wT4 + (size_t)z * D * D;
    } else if (z == 4) {
        K = D; N = FFD; src = w1 + (size_t)l * D * FFD; dst = w1T;
    } else {
        K = FFD; N = D; src = w2 + (size_t)l * FFD * D; dst = w2T;
    }
    const int n0 = blockIdx.x * 32, k0 = blockIdx.y * 32;
    if (n0 >= N || k0 >= K) return;
    const int tx = threadIdx.x & 31, ty = threadIdx.x >> 5;
#pragma unroll
    for (int i = 0; i < 4; ++i)
        t[ty + i * 8][tx] = src[(size_t)(k0 + ty + i * 8) * N + n0 + tx];
    __syncthreads();
#pragma unroll
    for (int i = 0; i < 4; ++i)
        dst[(size_t)(n0 + ty + i * 8) * K + k0 + tx] = f2b(t[tx][ty + i * 8]);
}

// ---------------- biases: bqkv [L][2304], buv [1536] -------------------------
__global__ __launch_bounds__(256) void concat_bias(const float* __restrict__ bq,
        const float* __restrict__ bk, const float* __restrict__ bv,
        const float* __restrict__ bu, const float* __restrict__ bvv,
        float* __restrict__ bqkv, float* __restrict__ buv) {
    const int i = blockIdx.x * 256 + threadIdx.x;
    if (i < LAY * D3) {
        const int l = i / D3, j = i % D3;
        bqkv[i] = j < D ? bq[l * D + j] : j < 2 * D ? bk[l * D + j - D] : bv[l * D + j - 2 * D];
    }
    const int k = i - LAY * D3;
    if (k >= 0 && k < 2 * D) buv[k] = k < D ? bu[k] : bvv[k - D];
}

// ---------------- bf16 MFMA GEMM: C = A[M,K] @ Bt[N,K]^T + bias -------------
// 128x64 tile, BK=32, dbuf 2-phase, global_load_lds. SPLITK: grid.z=2 slices.
// HEADMAJ: bf16 output remapped to kvh[3][H][TT][96] (QKV projection only).
template<int RELU, int SCALEQ, int SPLITK, int HEADMAJ>
__global__ __launch_bounds__(256) void gemm_mfma(const ushort_t* __restrict__ A,
        const ushort_t* __restrict__ Bt, const float* __restrict__ bias,
        float* __restrict__ Cf, float* __restrict__ Cf1,
        ushort_t* __restrict__ Cb, int M, int N, int K) {
    __shared__ ushort_t As[2][128 * 32];   // linear: row*32 + col
    __shared__ ushort_t Bs[2][64 * 32];
    const int tid = threadIdx.x;
    const int lane = tid & 63, w = tid >> 6;
    const int l15 = lane & 15, lg = lane >> 4;
    const int bm = blockIdx.y * 128, bn = blockIdx.x * 64;
    const int wm = (w >> 1) * 64, wn = (w & 1) * 32;
    const int trA0 = w * 32 + (lane >> 2);
    const int trA1 = trA0 + 16;
    const int trB  = w * 16 + (lane >> 2);
    const int sc   = (lane & 3) * 8;
    const size_t rowA0 = (size_t)min(bm + trA0, M - 1) * K;
    const size_t rowA1 = (size_t)min(bm + trA1, M - 1) * K;
    const size_t rowB  = (size_t)(bn + trB) * K;
    const int kbeg = SPLITK ? blockIdx.z * (K / 2) : 0;
    const int kend = SPLITK ? kbeg + K / 2 : K;

    f32x4 acc[4][2];
#pragma unroll
    for (int mi = 0; mi < 4; ++mi)
#pragma unroll
        for (int ni = 0; ni < 2; ++ni)
            acc[mi][ni] = (f32x4){0.f, 0.f, 0.f, 0.f};

    auto STAGE = [&](int buf, int k0) {
        gload16(A + rowA0 + k0 + sc, As[buf] + w * 1024);
        gload16(A + rowA1 + k0 + sc, As[buf] + w * 1024 + 512);
        gload16(Bt + rowB + k0 + sc, Bs[buf] + w * 512);
    };

    const int ntk = (kend - kbeg) / 32;
    STAGE(0, kbeg);
    __syncthreads();                       // vmcnt(0) drain: buf0 ready
    for (int t = 0; t < ntk; ++t) {
        const int buf = t & 1;
        if (t + 1 < ntk) STAGE(buf ^ 1, kbeg + (t + 1) * 32);
        bf16x8 af[4], bfr[2];
#pragma unroll
        for (int mi = 0; mi < 4; ++mi)
            af[mi] = *(const bf16x8*)&As[buf][(wm + mi * 16 + l15) * 32 + lg * 8];
#pragma unroll
        for (int ni = 0; ni < 2; ++ni)
            bfr[ni] = *(const bf16x8*)&Bs[buf][(wn + ni * 16 + l15) * 32 + lg * 8];
        __builtin_amdgcn_s_setprio(1);
#pragma unroll
        for (int mi = 0; mi < 4; ++mi)
#pragma unroll
            for (int ni = 0; ni < 2; ++ni)
                acc[mi][ni] = __builtin_amdgcn_mfma_f32_16x16x32_bf16(
                    af[mi], bfr[ni], acc[mi][ni], 0, 0, 0);
        __builtin_amdgcn_s_setprio(0);
        __syncthreads();                   // drains next-buf staging; guards reuse
    }
    float* Cout = (SPLITK && blockIdx.z) ? Cf1 : Cf;
    const bool addb = !(SPLITK && blockIdx.z);
#pragma unroll
    for (int mi = 0; mi < 4; ++mi)
#pragma unroll
        for (int ni = 0; ni < 2; ++ni)
#pragma unroll
            for (int r = 0; r < 4; ++r) {
                const int row = bm + wm + mi * 16 + lg * 4 + r;
                if (row >= M) continue;
                const int col = bn + wn + ni * 16 + l15;
                float v = acc[mi][ni][r] + (addb ? bias[col] : 0.f);
                if (RELU) v = fmaxf(v, 0.f);
                if (SCALEQ) { if (col < D) v *= 0.10206207261596577f; }
                if (Cout) Cout[(size_t)row * N + col] = v;
                if (Cb) {
                    if (HEADMAJ) {
                        const int m = col / D;            // 0=q 1=k 2=v
                        const int rem = col - m * D;
                        const int hd = rem / DKD;
                        const int dd = rem - hd * DKD;
                        Cb[(((size_t)m * H + hd) * TT + row) * DKD + dd] = f2b(v);
                    } else {
                        Cb[(size_t)row * N + col] = f2b(v);
                    }
                }
            }
}

// ---------------- flash-decoding attention over a KV chunk ------------------
// R11 structure; head-major kvh[3][H][TT][96]; grid (25, 8, 3).
__global__ __launch_bounds__(256) void attn_part(const ushort_t* __restrict__ kvh,
        ushort_t* __restrict__ Opart, float* __restrict__ ml) {
    __shared__ ushort_t Ks[64][104];     // K tile; reused as O-repack scratch
    __shared__ ushort_t Vt[96][72];      // transposed V, XOR slot swizzle
    __shared__ ushort_t Ps[4][16][72];   // per-wave P tile
    const int q0 = blockIdx.x * 64;
    const int h = blockIdx.y;
    const int cch = blockIdx.z;
    const int t_lo = (cch * QT) / NS;
    const int t_hi = ((cch + 1) * QT) / NS;
    const int tid = threadIdx.x;
    const int lane = tid & 63, w = tid >> 6;
    const int l15 = lane & 15, lg = lane >> 4;

    const ushort_t* Qb = kvh + (size_t)h * TT * DKD;
    const ushort_t* Kb = kvh + ((size_t)H + h) * TT * DKD;
    const ushort_t* Vb = kvh + ((size_t)2 * H + h) * TT * DKD;

    int r_[3], c_[3];
#pragma unroll
    for (int i = 0; i < 3; ++i) {
        const int ch = i * 256 + tid;
        r_[i] = ch / 12; c_[i] = (ch % 12) * 8;
    }
    // Q fragments in registers (pre-scaled by 1/sqrt(96))
    bf16x8 qfrag[3];
#pragma unroll
    for (int ks = 0; ks < 3; ++ks)
        qfrag[ks] = *(const bf16x8*)(Qb + (size_t)(q0 + w * 16 + l15) * DKD
                                     + ks * 32 + lg * 8);
    // prologue: first K/V tile into regs
    uint4 kreg[3], vreg[3];
    {
        const int s0 = t_lo * 64;
#pragma unroll
        for (int i = 0; i < 3; ++i) {
            kreg[i] = *(const uint4*)(Kb + (size_t)(s0 + r_[i]) * DKD + c_[i]);
            vreg[i] = *(const uint4*)(Vb + (size_t)(s0 + r_[i]) * DKD + c_[i]);
        }
    }
    float m_run[4], l_run[4];
    f32x4 acc_o[6];
#pragma unroll
    for (int r = 0; r < 4; ++r) { m_run[r] = -1e30f; l_run[r] = 0.f; }
#pragma unroll
    for (int nt = 0; nt < 6; ++nt) acc_o[nt] = (f32x4){0.f, 0.f, 0.f, 0.f};

    for (int t = t_lo; t < t_hi; ++t) {
        __syncthreads();                 // prev tile consumed
#pragma unroll
        for (int i = 0; i < 3; ++i) {
            *(uint4*)&Ks[r_[i]][c_[i]] = kreg[i];
            const ushort_t* pv = (const ushort_t*)&vreg[i];
            const int kk = r_[i] ^ (((c_[i] >> 3) & 7) << 3);   // slot swizzle
#pragma unroll
            for (int j = 0; j < 8; ++j) Vt[c_[i] + j][kk] = pv[j];
        }
        __syncthreads();
        if (t + 1 < t_hi) {              // issue next-tile loads early (T14)
            const int s0 = (t + 1) * 64;
#pragma unroll
            for (int i = 0; i < 3; ++i) {
                kreg[i] = *(const uint4*)(Kb + (size_t)(s0 + r_[i]) * DKD + c_[i]);
                vreg[i] = *(const uint4*)(Vb + (size_t)(s0 + r_[i]) * DKD + c_[i]);
            }
        }
        // S = Q K^T
        f32x4 accs[4];
#pragma unroll
        for (int ni = 0; ni < 4; ++ni) accs[ni] = (f32x4){0.f, 0.f, 0.f, 0.f};
        __builtin_amdgcn_s_setprio(1);
#pragma unroll
        for (int ks = 0; ks < 3; ++ks) {
#pragma unroll
            for (int ni = 0; ni < 4; ++ni) {
                const bf16x8 bk = *(const bf16x8*)&Ks[ni * 16 + l15][ks * 32 + lg * 8];
                accs[ni] = __builtin_amdgcn_mfma_f32_16x16x32_bf16(qfrag[ks], bk, accs[ni], 0, 0, 0);
            }
        }
        __builtin_amdgcn_s_setprio(0);
        // online softmax with defer-max (T13, THR=8)
        float mx[4];
#pragma unroll
        for (int r = 0; r < 4; ++r) {
            mx[r] = fmaxf(fmaxf(accs[0][r], accs[1][r]), fmaxf(accs[2][r], accs[3][r]));
#pragma unroll
            for (int o = 1; o <= 8; o <<= 1) mx[r] = fmaxf(mx[r], __shfl_xor(mx[r], o));
        }
        const bool grow = (mx[0] > m_run[0] + 8.f) || (mx[1] > m_run[1] + 8.f) ||
                          (mx[2] > m_run[2] + 8.f) || (mx[3] > m_run[3] + 8.f);
        if (__any(grow)) {
#pragma unroll
            for (int r = 0; r < 4; ++r) {
                const float mnew = fmaxf(m_run[r], mx[r]);
                const float sf = __expf(m_run[r] - mnew);
                m_run[r] = mnew;
                l_run[r] *= sf;
#pragma unroll
                for (int nt = 0; nt < 6; ++nt) acc_o[nt][r] *= sf;
            }
        }
        float ps[4][4];
#pragma unroll
        for (int r = 0; r < 4; ++r) {
            float rs = 0.f;
#pragma unroll
            for (int ni = 0; ni < 4; ++ni) {
                ps[ni][r] = __expf(accs[ni][r] - m_run[r]);
                rs += ps[ni][r];
            }
#pragma unroll
            for (int o = 1; o <= 8; o <<= 1) rs += __shfl_xor(rs, o);
            l_run[r] += rs;
        }
#pragma unroll
        for (int ni = 0; ni < 4; ++ni)
#pragma unroll
            for (int r = 0; r < 4; ++r)
                Ps[w][lg * 4 + r][ni * 16 + l15] = f2b(ps[ni][r]);
        // O += P @ V
        __builtin_amdgcn_s_setprio(1);
#pragma unroll
        for (int ks = 0; ks < 2; ++ks) {
            const bf16x8 ap = *(const bf16x8*)&Ps[w][l15][ks * 32 + lg * 8];
#pragma unroll
            for (int nt = 0; nt < 6; ++nt) {
                const int dim = nt * 16 + l15;
                const int kcol = (ks * 32 + lg * 8) ^ (((dim >> 3) & 7) << 3);
                const bf16x8 bv = *(const bf16x8*)&Vt[dim][kcol];
                acc_o[nt] = __builtin_amdgcn_mfma_f32_16x16x32_bf16(ap, bv, acc_o[nt], 0, 0, 0);
            }
        }
        __builtin_amdgcn_s_setprio(0);
    }
    // ---- epilogue: repack O via dead Ks LDS, then coalesced uint4 stores ----
    __syncthreads();                      // all waves done with Ks/Vt
    ushort_t* scr = &Ks[0][0] + w * (16 * 104);   // per-wave [16][104]
#pragma unroll
    for (int nt = 0; nt < 6; ++nt)
#pragma unroll
        for (int r = 0; r < 4; ++r)
            scr[(lg * 4 + r) * 104 + nt * 16 + l15] = f2b(acc_o[nt][r]);
    const size_t obase = (((size_t)cch * H + h) * TT + q0 + w * 16) * DKD;
#pragma unroll
    for (int ch = 0; ch < 3; ++ch) {
        const int idx = ch * 64 + lane;   // 0..191
        const int row = idx / 12;         // 0..15
        const int c16 = (idx % 12) * 8;   // 0..88 step 8
        const uint4 v = *(const uint4*)&scr[row * 104 + c16];
        *(uint4*)(Opart + obase + (size_t)row * DKD + c16) = v;
    }
    if (l15 == 0) {
#pragma unroll
        for (int r = 0; r < 4; ++r) {
            const int row = q0 + w * 16 + lg * 4 + r;
            float2* mlp = (float2*)ml;
            mlp[((size_t)cch * H + h) * TT + row] = make_float2(m_run[r], l_run[r]);
        }
    }
}

// ---------------- combine NS partials, wave-per-row, vectorized -------------
__global__ __launch_bounds__(256) void attn_combine(const ushort_t* __restrict__ Opart,
        const float* __restrict__ ml, ushort_t* __restrict__ O) {
    const int lane = threadIdx.x & 63, w = threadIdx.x >> 6;
    const int row = blockIdx.x * 4 + w;
    const int hd = lane >> 3;            // head
    const int co = (lane & 7) * 12;      // col offset within head
    const float2* mlp = (const float2*)ml;
    float m[NS], l[NS], M = -1e30f;
#pragma unroll
    for (int c = 0; c < NS; ++c) {
        const float2 v = mlp[((size_t)c * H + hd) * TT + row];
        m[c] = v.x; l[c] = v.y; M = fmaxf(M, m[c]);
    }
    float e[NS], L = 0.f;
#pragma unroll
    for (int c = 0; c < NS; ++c) { e[c] = __expf(m[c] - M); L += l[c] * e[c]; }
    const float invL = 1.f / L;
    float o[12] = {};
#pragma unroll
    for (int c = 0; c < NS; ++c) {
        const ushort_t* p = Opart + (((size_t)c * H + hd) * TT + row) * DKD + co;
#pragma unroll
        for (int j = 0; j < 3; ++j) {
            const ushort4 v4 = *(const ushort4*)(p + j * 4);
            o[j * 4 + 0] += b2f(v4.x) * e[c];
            o[j * 4 + 1] += b2f(v4.y) * e[c];
            o[j * 4 + 2] += b2f(v4.z) * e[c];
            o[j * 4 + 3] += b2f(v4.w) * e[c];
        }
    }
    ushort_t* q = O + (size_t)row * D + hd * DKD + co;
#pragma unroll
    for (int j = 0; j < 3; ++j) {
        ushort4 u;
        u.x = f2b(o[j * 4 + 0] * invL); u.y = f2b(o[j * 4 + 1] * invL);
        u.z = f2b(o[j * 4 + 2] * invL); u.w = f2b(o[j * 4 + 3] * invL);
        *(ushort4*)(q + j * 4) = u;
    }
}

// ---------------- x = LN(x + y0 + y1); wave-per-row, shfl-only --------------
__global__ __launch_bounds__(256) void add_ln3(float* __restrict__ x,
        const float* __restrict__ y0, const float* __restrict__ y1,
        const float* __restrict__ g, const float* __restrict__ b,
        ushort_t* __restrict__ xb) {
    const int lane = threadIdx.x & 63, w = threadIdx.x >> 6;
    const int row = blockIdx.x * 4 + w;
    const size_t base = (size_t)row * D;
    float4 t[3];
    float s = 0.f, s2 = 0.f;
#pragma unroll
    for (int i = 0; i < 3; ++i) {
        const int c = lane * 4 + i * 256;
        const float4 xv = *(const float4*)(x + base + c);
        const float4 a0 = *(const float4*)(y0 + base + c);
        const float4 a1 = *(const float4*)(y1 + base + c);
        t[i].x = xv.x + a0.x + a1.x; t[i].y = xv.y + a0.y + a1.y;
        t[i].z = xv.z + a0.z + a1.z; t[i].w = xv.w + a0.w + a1.w;
        s += t[i].x + t[i].y + t[i].z + t[i].w;
        s2 += t[i].x * t[i].x + t[i].y * t[i].y + t[i].z * t[i].z + t[i].w * t[i].w;
    }
#pragma unroll
    for (int o = 32; o >= 1; o >>= 1) { s += __shfl_xor(s, o); s2 += __shfl_xor(s2, o); }
    const float mean = s * (1.f / 768.f);
    const float var = s2 * (1.f / 768.f) - mean * mean;
    const float inv = rsqrtf(var + 1e-5f);
#pragma unroll
    for (int i = 0; i < 3; ++i) {
        const int c = lane * 4 + i * 256;
        float4 o4;
        o4.x = (t[i].x - mean) * inv * g[c + 0] + b[c + 0];
        o4.y = (t[i].y - mean) * inv * g[c + 1] + b[c + 1];
        o4.z = (t[i].z - mean) * inv * g[c + 2] + b[c + 2];
        o4.w = (t[i].w - mean) * inv * g[c + 3] + b[c + 3];
        *(float4*)(x + base + c) = o4;
        ushort4 u;
        u.x = f2b(o4.x); u.y = f2b(o4.y); u.z = f2b(o4.z); u.w = f2b(o4.w);
        *(ushort4*)(xb + base + c) = u;
    }
}

// ---------------- predictor -------------------------------------------------
__global__ __launch_bounds__(256) void predict_k(const float* __restrict__ x,
        const float* __restrict__ pw, const float* __restrict__ pb,
        float* __restrict__ out) {
    __shared__ float red[4];
    const int r = blockIdx.x;
    const int tid = threadIdx.x;
    float best = -1e30f;
    for (int bag = 0; bag < BAG; ++bag) {
        const int row = (bag * SPANS) * E + (bag * SPANS + 1);
        const float* f = x + (size_t)row * D;
        float acc = 0.f;
        for (int d = tid; d < D; d += 256) acc += f[d] * pw[(size_t)d * NREL + r];
        best = fmaxf(best, block_sum(acc, red));
    }
    if (tid == 0) out[r] = best + pb[r];
}

extern "C" void kernel_launch(void* const* d_in, const int* in_sizes, int n_in,
                              void* d_out, int out_size, void* d_ws, size_t ws_size,
                              hipStream_t stream) {
    const float* emb  = (const float*)d_in[0];
    const int*  spans = (const int*)d_in[1];
    const float* wu_w = (const float*)d_in[2];  const float* wu_b = (const float*)d_in[3];
    const float* wvv_w= (const float*)d_in[4];  const float* wvv_b= (const float*)d_in[5];
    const float* lnr_w= (const float*)d_in[6];  const float* lnr_b= (const float*)d_in[7];
    const float* wq = (const float*)d_in[8];    const float* bq = (const float*)d_in[9];
    const float* wk = (const float*)d_in[10];   const float* bk = (const float*)d_in[11];
    const float* wv = (const float*)d_in[12];   const float* bv = (const float*)d_in[13];
    const float* wo = (const float*)d_in[14];   const float* bo = (const float*)d_in[15];
    const float* w1 = (const float*)d_in[16];   const float* b1 = (const float*)d_in[17];
    const float* w2 = (const float*)d_in[18];   const float* b2 = (const float*)d_in[19];
    const float* g1 = (const float*)d_in[20];   const float* be1= (const float*)d_in[21];
    const float* g2 = (const float*)d_in[22];   const float* be2= (const float*)d_in[23];
    const float* pw = (const float*)d_in[24];   const float* pb = (const float*)d_in[25];

    // workspace layout (~36 MB). Aliases: Opart = tb+fb; tb1 = kvh region.
    char* cur = (char*)d_ws;
    auto alloc = [&](size_t bytes) { char* p = cur; cur += (bytes + 255) & ~(size_t)255; return p; };
    ushort_t* htb  = (ushort_t*)alloc(E * D * 2);
    float*    uvb  = (float*)alloc((size_t)E * 1536 * 4);
    float*    part = (float*)alloc((size_t)E * 8 * D * 4);   // span partials; reused as ml
    float*    x    = (float*)alloc((size_t)TT * D * 4);
    ushort_t* xb   = (ushort_t*)alloc((size_t)TT * D * 2);
    ushort_t* kvh  = (ushort_t*)alloc((size_t)3 * H * TT * DKD * 2); // head-major QKV
    ushort_t* ob   = (ushort_t*)alloc((size_t)TT * D * 2);   // alpha, then attn out
    float*    tb   = (float*)alloc((size_t)TT * D * 4);      // adjacent ...
    ushort_t* fb   = (ushort_t*)alloc((size_t)TT * FFD * 2); // ... to tb
    ushort_t* wT4  = (ushort_t*)alloc((size_t)4 * D * D * 2);
    ushort_t* w1T  = (ushort_t*)alloc((size_t)D * FFD * 2);
    ushort_t* w2T  = (ushort_t*)alloc((size_t)FFD * D * 2);
    float*    bqkv = (float*)alloc((size_t)LAY * D3 * 4);
    float*    buv  = (float*)alloc((size_t)2 * D * 4);
    ushort_t* Opart = (ushort_t*)tb;    // NS*H*TT*DKD*2 = 7.37 MB <= tb+fb (8.2 MB)
    float*    ml    = part;             // 300 KB <= part
    ushort_t* wuvT  = wT4;              // [1536][768], used before layer 0
    ushort_t* lnrT  = w1T;              // [768][768], used before layer 0
    float*    tb1   = (float*)kvh;      // split-K partial; kvh dead when used

    const int DD = D * D;

    span_pool_p1<<<dim3(E, 8), 256, 0, stream>>>(emb, spans, part);
    span_pool_p2<<<E, 256, 0, stream>>>(part, htb);
    transpose_up<<<dim3(24, 24, 3), 256, 0, stream>>>(lnr_w, wu_w, wvv_w, lnrT, wuvT);
    concat_bias<<<(LAY * D3 + 2 * D + 255) / 256, 256, 0, stream>>>(bq, bk, bv, wu_b, wvv_b, bqkv, buv);
    gemm_mfma<0, 0, 0, 0><<<dim3(1536 / 64, 1), 256, 0, stream>>>(
        htb, wuvT, buv, uvb, nullptr, nullptr, E, 1536, D);
    alpha_k<<<TT, 256, 0, stream>>>(uvb, ob);
    gemm_mfma<1, 0, 0, 0><<<dim3(D / 64, (TT + 127) / 128), 256, 0, stream>>>(
        ob, lnrT, lnr_b, x, nullptr, xb, TT, D, D);

    for (int l = 0; l < LAY; ++l) {
        transpose_layer<<<dim3(32, 32, 6), 256, 0, stream>>>(wq, wk, wv, wo, w1, w2, l, wT4, w1T, w2T);
        // fused QKV projection, head-major bf16 out (Q pre-scaled by 1/sqrt(96))
        gemm_mfma<0, 1, 0, 1><<<dim3(D3 / 64, (TT + 127) / 128), 256, 0, stream>>>(
            xb, wT4, bqkv + l * D3, nullptr, nullptr, kvh, TT, D3, D);
        attn_part<<<dim3(QT, H, NS), 256, 0, stream>>>(kvh, Opart, ml);
        attn_combine<<<TT / 4, 256, 0, stream>>>(Opart, ml, ob);
        // wo: split-K=2 -> tb (slice0 +bias) / tb1 (slice1)
        gemm_mfma<0, 0, 1, 0><<<dim3(D / 64, (TT + 127) / 128, 2), 256, 0, stream>>>(
            ob, wT4 + 3 * DD, bo + l * D, tb, tb1, nullptr, TT, D, D);
        add_ln3<<<TT / 4, 256, 0, stream>>>(x, tb, tb1, g1 + l * D, be1 + l * D, xb);
        gemm_mfma<1, 0, 0, 0><<<dim3(FFD / 64, (TT + 127) / 128), 256, 0, stream>>>(
            xb, w1T, b1 + l * FFD, nullptr, nullptr, fb, TT, FFD, D);
        // ff2: split-K=2 (K=1024) -> tb / tb1
        gemm_mfma<0, 0, 1, 0><<<dim3(D / 64, (TT + 127) / 128, 2), 256, 0, stream>>>(
            fb, w2T, b2 + l * D, tb, tb1, nullptr, TT, D, FFD);
        add_ln3<<<TT / 4, 256, 0, stream>>>(x, tb, tb1, g2 + l * D, be2 + l * D, xb);
    }

    predict_k<<<NREL, 256, 0, stream>>>(x, pw, pb, (float*)d_out);
    (void)in_sizes; (void)n_in; (void)out_size; (void)ws_size;
}